// Round 5
// baseline (803.400 us; speedup 1.0000x reference)
//
#include <hip/hip_runtime.h>

#define IN_DIM 40
#define HID 64
#define TSTEPS 500
#define CHAINS 16          // chains per block
#define KDIM 128           // K = h(64) | x(40 @ k=64..103) | zero pad

typedef _Float16 half2v __attribute__((ext_vector_type(2)));
typedef _Float16 half8  __attribute__((ext_vector_type(8)));
typedef float    f32x4  __attribute__((ext_vector_type(4)));

__device__ __forceinline__ float sigmoid_fast(float x) {
    return __builtin_amdgcn_rcpf(1.0f + __expf(-x));
}

__device__ __forceinline__ float tanh_fast(float x) {
    float ax = fabsf(x);
    float e = __expf(-2.0f * ax);
    float r = (1.0f - e) * __builtin_amdgcn_rcpf(1.0f + e);
    return copysignf(r, x);
}

// raw barrier: LDS visibility only; in-flight global loads (vmcnt) survive.
__device__ __forceinline__ void block_sync_lds() {
    asm volatile("s_waitcnt lgkmcnt(0)" ::: "memory");
    __builtin_amdgcn_s_barrier();
    asm volatile("" ::: "memory");
}

// ---------------- Kernel A: cast x to f16 (contiguous layout preserved) -------------
__global__ __launch_bounds__(256)
void xcast_kernel(const float* __restrict__ x, unsigned short* __restrict__ xf, int n4)
{
    int idx    = blockIdx.x * 256 + threadIdx.x;
    int stride = gridDim.x * 256;
    for (int i = idx; i < n4; i += stride) {
        float4 v = reinterpret_cast<const float4*>(x)[i];
        half2v a  = { (_Float16)v.x, (_Float16)v.y };
        half2v bb = { (_Float16)v.z, (_Float16)v.w };
        uint2 o = { __builtin_bit_cast(uint, a), __builtin_bit_cast(uint, bb) };
        reinterpret_cast<uint2*>(xf)[i] = o;
    }
}

// ---------------- Kernel B: MFMA recurrence, 16 chains / block, 4 waves --------------
// Z[256 gates x 16 chains] = W[256 x 128] . slab[128 x 16] via 16x16x32_f16 MFMA.
// Wave w owns gate-type w (rows 64w..64w+63). D layout (verified): col=lane&15 (chain),
// row=4*(lane>>4)+reg (gate-within-tile).
__global__ __launch_bounds__(256, 1)
void lstm_mfma(const unsigned short* __restrict__ xf,
               const float* __restrict__ W_ih,
               const float* __restrict__ W_hh,
               const float* __restrict__ b_ih,
               const float* __restrict__ b_hh,
               const float* __restrict__ fc1_w,
               const float* __restrict__ fc1_b,
               const float* __restrict__ fc2_w,
               const float* __restrict__ fc2_b,
               float* __restrict__ out)
{
    const int tid = threadIdx.x;
    const int w   = tid >> 6;        // wave id = gate type (0=i 1=f 2=g 3=o)
    const int l   = tid & 63;
    const int lr  = l & 15;          // A-row / B-col lane index
    const int lg  = l >> 4;          // k-group
    const int blk = blockIdx.x;

    __shared__ __align__(16) unsigned short slab[CHAINS][KDIM]; // 4 KB, swizzled rows
    __shared__ float act[4][HID][CHAINS];                       // 16 KB
    __shared__ float h32[CHAINS][HID];                          // 4 KB
    __shared__ float rl [CHAINS][HID];                          // 4 KB

    // ---- zero slab (h=0, pad=0); 256 thr x 16B = 4096 B ----
    reinterpret_cast<uint4*>(slab)[tid] = uint4{0, 0, 0, 0};

    // ---- persistent W fragments + bias (per lane, this wave's 64 gate rows) ----
    // A-frag for tile j, K-tile kt: row m=lr -> gate 64w+16j+lr, k = kt*32+lg*8 .. +7
    half8 wfrag[4][4];
    float biasr[4][4];
    #pragma unroll
    for (int j = 0; j < 4; ++j) {
        const int gate = w * 64 + j * 16 + lr;
        #pragma unroll
        for (int kt = 0; kt < 4; ++kt) {
            const int k0 = kt * 32 + lg * 8;
            float v[8];
            if (k0 < 64) {
                const float4* p = reinterpret_cast<const float4*>(W_hh + (size_t)gate * HID + k0);
                float4 q0 = p[0], q1 = p[1];
                v[0]=q0.x; v[1]=q0.y; v[2]=q0.z; v[3]=q0.w;
                v[4]=q1.x; v[5]=q1.y; v[6]=q1.z; v[7]=q1.w;
            } else if (k0 < 104) {
                const float4* p = reinterpret_cast<const float4*>(W_ih + (size_t)gate * IN_DIM + (k0 - 64));
                float4 q0 = p[0], q1 = p[1];
                v[0]=q0.x; v[1]=q0.y; v[2]=q0.z; v[3]=q0.w;
                v[4]=q1.x; v[5]=q1.y; v[6]=q1.z; v[7]=q1.w;
            } else {
                #pragma unroll
                for (int e = 0; e < 8; ++e) v[e] = 0.0f;
            }
            half8 hv;
            #pragma unroll
            for (int e = 0; e < 8; ++e) hv[e] = (_Float16)v[e];
            wfrag[j][kt] = hv;
        }
        // D row r of tile j -> gate 64w+16j+4*lg+r
        #pragma unroll
        for (int r = 0; r < 4; ++r) {
            const int g2 = w * 64 + j * 16 + 4 * lg + r;
            biasr[j][r] = b_ih[g2] + b_hh[g2];
        }
    }

    // ---- x streaming: 16 chains x 40 f16 = 160 x uint2 per step ----
    const int  xc   = tid / 10;                  // chain (tid<160)
    const int  xseg = tid - xc * 10;             // 8B segment within row
    const bool xact = (tid < 160);
    const char* xgbase = reinterpret_cast<const char*>(xf)
                       + ((size_t)(blk * CHAINS + xc) * TSTEPS) * (IN_DIM * 2)
                       + xseg * 8;
    const int  xrow_byte = (128 + xseg * 8);     // k=64.. region, pre-swizzle
    const int  xaddr = xc * 256 + (xrow_byte ^ ((xc & 7) << 4));

    // stage x_0, prefetch x_1
    uint2 xA = {0, 0}, xB = {0, 0};
    if (xact) {
        uint2 x0 = *reinterpret_cast<const uint2*>(xgbase);
        *reinterpret_cast<uint2*>(reinterpret_cast<char*>(slab) + xaddr) = x0;
        xA = *reinterpret_cast<const uint2*>(xgbase + 80);
    }
    block_sync_lds();

    // ---- per-thread cell state: chain c2 = tid&15, units u = a2 + 16k ----
    const int c2 = tid & 15;
    const int a2 = tid >> 4;
    float cs[4] = {0.f, 0.f, 0.f, 0.f};

    #pragma unroll 1
    for (int t = 0; t < TSTEPS; ++t) {
        // ---------- phase 1: MFMA + activation ----------
        // issue x_{t+2} prefetch (stays in flight across barriers; no vmcnt drain)
        if (xact) {
            const int tp = (t + 2 < TSTEPS) ? t + 2 : TSTEPS - 1;
            xB = *reinterpret_cast<const uint2*>(xgbase + (size_t)tp * 80);
        }
        // B-frags: col n=lr -> chain lr, k = kt*32+lg*8 (swizzled b128 reads)
        half8 bf[4];
        #pragma unroll
        for (int kt = 0; kt < 4; ++kt) {
            const int addr = lr * 256 + (((kt * 64) + lg * 16) ^ ((lr & 7) << 4));
            uint4 q = *reinterpret_cast<const uint4*>(reinterpret_cast<const char*>(slab) + addr);
            bf[kt] = __builtin_bit_cast(half8, q);
        }
        #pragma unroll
        for (int j = 0; j < 4; ++j) {
            f32x4 acc = { biasr[j][0], biasr[j][1], biasr[j][2], biasr[j][3] };
            #pragma unroll
            for (int kt = 0; kt < 4; ++kt)
                acc = __builtin_amdgcn_mfma_f32_16x16x32_f16(wfrag[j][kt], bf[kt], acc, 0, 0, 0);
            #pragma unroll
            for (int r = 0; r < 4; ++r) {
                float z = acc[r];
                float a = (w == 2) ? tanh_fast(z) : sigmoid_fast(z);
                act[w][j * 16 + 4 * lg + r][lr] = a;
            }
        }
        block_sync_lds();   // barrier 1: activations visible

        // ---------- phase 2: elementwise c,h + slab rewrite ----------
        const bool lastt = (t == TSTEPS - 1);
        #pragma unroll
        for (int k = 0; k < 4; ++k) {
            const int u = a2 + 16 * k;
            float iv = act[0][u][c2];
            float fv = act[1][u][c2];
            float gv = act[2][u][c2];
            float ov = act[3][u][c2];
            cs[k] = fmaf(fv, cs[k], iv * gv);
            float h = ov * tanh_fast(cs[k]);
            if (lastt) {
                h32[c2][u] = h;
            } else {
                const int haddr = c2 * 256 + ((u * 2) ^ ((c2 & 7) << 4));
                _Float16 hf = (_Float16)h;
                *reinterpret_cast<unsigned short*>(reinterpret_cast<char*>(slab) + haddr) =
                    __builtin_bit_cast(unsigned short, hf);
            }
        }
        // write x_{t+1} into slab (loaded 1.5 steps ago)
        if (!lastt && xact)
            *reinterpret_cast<uint2*>(reinterpret_cast<char*>(slab) + xaddr) = xA;
        xA = xB;
        block_sync_lds();   // barrier 2: slab ready for next step
    }

    // ---- epilogue: fc1 + relu (wave w handles chains 4w..4w+3), then fc2 ----
    {
        float4 wrow[16];
        const float4* fwp = reinterpret_cast<const float4*>(fc1_w + (size_t)l * HID);
        #pragma unroll
        for (int q = 0; q < 16; ++q) wrow[q] = fwp[q];
        const float b1 = fc1_b[l];
        #pragma unroll
        for (int cc = 0; cc < 4; ++cc) {
            const int chain = 4 * w + cc;
            float acc = b1;
            #pragma unroll
            for (int q = 0; q < 16; ++q) {
                float4 hv = reinterpret_cast<const float4*>(&h32[chain][0])[q];
                acc = fmaf(wrow[q].x, hv.x, acc);
                acc = fmaf(wrow[q].y, hv.y, acc);
                acc = fmaf(wrow[q].z, hv.z, acc);
                acc = fmaf(wrow[q].w, hv.w, acc);
            }
            rl[chain][l] = fmaxf(acc, 0.0f);
        }
    }
    __syncthreads();
    if (tid < 32) {
        const int c = tid >> 1;
        const int o = tid & 1;
        float acc = fc2_b[o];
        for (int k = 0; k < HID; ++k)
            acc = fmaf(fc2_w[o * HID + k], rl[c][k], acc);
        out[(size_t)(blk * CHAINS + c) * 2 + o] = acc;
    }
}

extern "C" void kernel_launch(void* const* d_in, const int* in_sizes, int n_in,
                              void* d_out, int out_size, void* d_ws, size_t ws_size,
                              hipStream_t stream) {
    const float* x     = (const float*)d_in[0];
    const float* W_ih  = (const float*)d_in[1];
    const float* W_hh  = (const float*)d_in[2];
    const float* b_ih  = (const float*)d_in[3];
    const float* b_hh  = (const float*)d_in[4];
    const float* fc1_w = (const float*)d_in[5];
    const float* fc1_b = (const float*)d_in[6];
    const float* fc2_w = (const float*)d_in[7];
    const float* fc2_b = (const float*)d_in[8];
    float* out = (float*)d_out;

    const int B = in_sizes[0] / (TSTEPS * IN_DIM);   // 1024

    unsigned short* xf16 = (unsigned short*)d_ws;    // 40 MB f16 copy of x

    const int n4 = B * TSTEPS * IN_DIM / 4;
    xcast_kernel<<<2048, 256, 0, stream>>>(x, xf16, n4);
    lstm_mfma<<<B / CHAINS, 256, 0, stream>>>(xf16, W_ih, W_hh, b_ih, b_hh,
                                              fc1_w, fc1_b, fc2_w, fc2_b, out);
}

// Round 6
// 282.601 us; speedup vs baseline: 2.8429x; 2.8429x over previous
//
#include <hip/hip_runtime.h>

#define IN_DIM 40
#define HID 64
#define TSTEPS 500
#define CHAINS 16          // chains per block
#define KDIM 128           // K = h(64) | x(40 @ k=64..103) | zero pad

typedef _Float16 half2v __attribute__((ext_vector_type(2)));
typedef _Float16 half8  __attribute__((ext_vector_type(8)));
typedef float    f32x4  __attribute__((ext_vector_type(4)));

__device__ __forceinline__ float sigmoid_fast(float x) {
    return __builtin_amdgcn_rcpf(1.0f + __expf(-x));
}

__device__ __forceinline__ float tanh_fast(float x) {
    float ax = fabsf(x);
    float e = __expf(-2.0f * ax);
    float r = (1.0f - e) * __builtin_amdgcn_rcpf(1.0f + e);
    return copysignf(r, x);
}

// LDS-visibility barrier: does NOT drain vmcnt (in-flight global prefetch survives).
__device__ __forceinline__ void block_sync_lds() {
    asm volatile("s_waitcnt lgkmcnt(0)" ::: "memory");
    __builtin_amdgcn_s_barrier();
    __builtin_amdgcn_sched_barrier(0);
}

// Single fused kernel: MFMA recurrence, 16 chains/block, 4 waves, gate-interleaved rows.
// W'[r'] = W[(r'&3)*64 + (r'>>2)]  =>  m-tile j holds gates i,f,g,o of units 4j..4j+3.
// D layout (verified m89): col=lane&15 (chain), row=4*(lane>>4)+reg.
// => lane's acc[reg] = gate `reg` of unit 4*jt+lg, chain lr: cell update is lane-local.
__global__ __launch_bounds__(256, 1)
void lstm_mfma(const float* __restrict__ x,
               const float* __restrict__ W_ih,
               const float* __restrict__ W_hh,
               const float* __restrict__ b_ih,
               const float* __restrict__ b_hh,
               const float* __restrict__ fc1_w,
               const float* __restrict__ fc1_b,
               const float* __restrict__ fc2_w,
               const float* __restrict__ fc2_b,
               float* __restrict__ out)
{
    const int tid = threadIdx.x;
    const int w   = tid >> 6;        // wave id: owns m-tiles 4w..4w+3 (units 16w..16w+15)
    const int l   = tid & 63;
    const int lr  = l & 15;          // A-row / B-col (chain) lane index
    const int lg  = l >> 4;          // k-group / D-row group
    const int blk = blockIdx.x;

    __shared__ __align__(16) unsigned short slab[2][CHAINS][KDIM]; // 8 KB, parity dbuf
    __shared__ float h32[CHAINS][HID];                             // 4 KB (final h)
    __shared__ float rl [CHAINS][HID];                             // 4 KB (relu out)

    // ---- zero both slab parities: 256 thr x 32 B ----
    {
        uint4* p = reinterpret_cast<uint4*>(slab);
        p[tid]       = uint4{0, 0, 0, 0};
        p[tid + 256] = uint4{0, 0, 0, 0};
    }

    // ---- persistent A-fragments (gate-interleaved rows) + bias ----
    // tile j (global jt=4w+j), A row m=lr -> unit 4*jt+(lr>>2), gate lr&3.
    half8 wfrag[4][4];
    float biasr[4][4];
    #pragma unroll
    for (int j = 0; j < 4; ++j) {
        const int jt   = 4 * w + j;
        const int unit = 4 * jt + (lr >> 2);
        const int gate = lr & 3;
        const int row  = gate * HID + unit;          // original W row
        #pragma unroll
        for (int kt = 0; kt < 4; ++kt) {
            const int k0 = kt * 32 + lg * 8;
            float v[8];
            if (k0 < 64) {
                const float4* p = reinterpret_cast<const float4*>(W_hh + (size_t)row * HID + k0);
                float4 q0 = p[0], q1 = p[1];
                v[0]=q0.x; v[1]=q0.y; v[2]=q0.z; v[3]=q0.w;
                v[4]=q1.x; v[5]=q1.y; v[6]=q1.z; v[7]=q1.w;
            } else if (k0 < 104) {
                const float4* p = reinterpret_cast<const float4*>(W_ih + (size_t)row * IN_DIM + (k0 - 64));
                float4 q0 = p[0], q1 = p[1];
                v[0]=q0.x; v[1]=q0.y; v[2]=q0.z; v[3]=q0.w;
                v[4]=q1.x; v[5]=q1.y; v[6]=q1.z; v[7]=q1.w;
            } else {
                #pragma unroll
                for (int e = 0; e < 8; ++e) v[e] = 0.0f;
            }
            half8 hv;
            #pragma unroll
            for (int e = 0; e < 8; ++e) hv[e] = (_Float16)v[e];
            wfrag[j][kt] = hv;
        }
        // D rows 4lg+reg -> gate reg of unit 4*jt+lg
        const int ud = 4 * jt + lg;
        #pragma unroll
        for (int r = 0; r < 4; ++r)
            biasr[j][r] = b_ih[r * HID + ud] + b_hh[r * HID + ud];
    }

    // ---- x staging lanes: 16 chains x 160 B f32 -> 160 lanes x 16 B ----
    const int  xc   = tid / 10;                  // chain
    const int  xseg = tid - xc * 10;             // 16B f32 segment (4 elems)
    const bool xact = (tid < 160);
    const float* xgbase = x + ((size_t)(blk * CHAINS + xc) * TSTEPS) * IN_DIM + xseg * 4;
    const int  xoff = xc * 256 + ((128 + 8 * xseg) ^ ((xc & 7) << 4));  // byte in slab[p]

    auto xstore = [&](int par, const float4& v) {
        half2v lo = { (_Float16)v.x, (_Float16)v.y };
        half2v hi = { (_Float16)v.z, (_Float16)v.w };
        uint2 o = { __builtin_bit_cast(uint, lo), __builtin_bit_cast(uint, hi) };
        *reinterpret_cast<uint2*>(reinterpret_cast<char*>(slab) + par * 4096 + xoff) = o;
    };

    // prologue: stage x_0 into slab[0]; prefetch x_1
    float4 fA = {0,0,0,0}, fB = {0,0,0,0};
    if (xact) {
        float4 x0 = *reinterpret_cast<const float4*>(xgbase);
        xstore(0, x0);
        fA = *reinterpret_cast<const float4*>(xgbase + IN_DIM);
    }
    __syncthreads();   // one-time full drain

    float cs[4] = {0.f, 0.f, 0.f, 0.f};
    float hreg[4];

    // one step: reads slab[par], writes slab[par^1]; `cur` holds x_{t+1}, `nxt` gets x_{t+2}
    auto step = [&](int t, int par, const float4& cur, float4& nxt) {
        const bool lastt = (t == TSTEPS - 1);
        // issue x_{t+2} prefetch (first used in NEXT step's phase 2 -> ~1 step to land)
        if (xact) {
            const int tp = (t + 2 < TSTEPS) ? t + 2 : TSTEPS - 1;
            nxt = *reinterpret_cast<const float4*>(xgbase + (size_t)tp * IN_DIM);
        }
        // B-frags from slab[par]: col=lr (chain), k = kt*32+lg*8 (swizzled b128)
        half8 bf[4];
        #pragma unroll
        for (int kt = 0; kt < 4; ++kt) {
            const int addr = par * 4096 + lr * 256 + (((kt * 64) + lg * 16) ^ ((lr & 7) << 4));
            uint4 q = *reinterpret_cast<const uint4*>(reinterpret_cast<const char*>(slab) + addr);
            bf[kt] = __builtin_bit_cast(half8, q);
        }
        #pragma unroll
        for (int j = 0; j < 4; ++j) {
            f32x4 acc = { biasr[j][0], biasr[j][1], biasr[j][2], biasr[j][3] };
            #pragma unroll
            for (int kt = 0; kt < 4; ++kt)
                acc = __builtin_amdgcn_mfma_f32_16x16x32_f16(wfrag[j][kt], bf[kt], acc, 0, 0, 0);
            // acc = {z_i, z_f, z_g, z_o} of (unit 4*(4w+j)+lg, chain lr) — lane-local cell
            float iv = sigmoid_fast(acc[0]);
            float fv = sigmoid_fast(acc[1]);
            float gv = tanh_fast(acc[2]);
            float ov = sigmoid_fast(acc[3]);
            cs[j] = fmaf(fv, cs[j], iv * gv);
            hreg[j] = ov * tanh_fast(cs[j]);
        }
        if (lastt) {
            #pragma unroll
            for (int j = 0; j < 4; ++j)
                h32[lr][4 * (4 * w + j) + lg] = hreg[j];
        } else {
            #pragma unroll
            for (int j = 0; j < 4; ++j) {
                const int u = 4 * (4 * w + j) + lg;
                const int haddr = (par ^ 1) * 4096 + lr * 256 + ((u * 2) ^ ((lr & 7) << 4));
                _Float16 hf = (_Float16)hreg[j];
                *reinterpret_cast<unsigned short*>(reinterpret_cast<char*>(slab) + haddr) =
                    __builtin_bit_cast(unsigned short, hf);
            }
            if (xact) xstore(par ^ 1, cur);   // x_{t+1} into next parity
        }
        block_sync_lds();   // the ONLY barrier per step (no vmcnt drain)
    };

    #pragma unroll 1
    for (int t = 0; t < TSTEPS; t += 2) {
        step(t,     0, fA, fB);
        step(t + 1, 1, fB, fA);
    }

    // ---- epilogue: fc1 + relu (wave w -> chains 4w..4w+3), then fc2 ----
    {
        float4 wrow[16];
        const float4* fwp = reinterpret_cast<const float4*>(fc1_w + (size_t)l * HID);
        #pragma unroll
        for (int q = 0; q < 16; ++q) wrow[q] = fwp[q];
        const float b1 = fc1_b[l];
        #pragma unroll
        for (int cc = 0; cc < 4; ++cc) {
            const int chain = 4 * w + cc;
            float acc = b1;
            #pragma unroll
            for (int q = 0; q < 16; ++q) {
                float4 hv = reinterpret_cast<const float4*>(&h32[chain][0])[q];
                acc = fmaf(wrow[q].x, hv.x, acc);
                acc = fmaf(wrow[q].y, hv.y, acc);
                acc = fmaf(wrow[q].z, hv.z, acc);
                acc = fmaf(wrow[q].w, hv.w, acc);
            }
            rl[chain][l] = fmaxf(acc, 0.0f);
        }
    }
    __syncthreads();
    if (tid < 32) {
        const int c = tid >> 1;
        const int o = tid & 1;
        float acc = fc2_b[o];
        for (int k = 0; k < HID; ++k)
            acc = fmaf(fc2_w[o * HID + k], rl[c][k], acc);
        out[(size_t)(blk * CHAINS + c) * 2 + o] = acc;
    }
}

extern "C" void kernel_launch(void* const* d_in, const int* in_sizes, int n_in,
                              void* d_out, int out_size, void* d_ws, size_t ws_size,
                              hipStream_t stream) {
    const float* x     = (const float*)d_in[0];
    const float* W_ih  = (const float*)d_in[1];
    const float* W_hh  = (const float*)d_in[2];
    const float* b_ih  = (const float*)d_in[3];
    const float* b_hh  = (const float*)d_in[4];
    const float* fc1_w = (const float*)d_in[5];
    const float* fc1_b = (const float*)d_in[6];
    const float* fc2_w = (const float*)d_in[7];
    const float* fc2_b = (const float*)d_in[8];
    float* out = (float*)d_out;

    const int B = in_sizes[0] / (TSTEPS * IN_DIM);   // 1024
    lstm_mfma<<<B / CHAINS, 256, 0, stream>>>(x, W_ih, W_hh, b_ih, b_hh,
                                              fc1_w, fc1_b, fc2_w, fc2_b, out);
}